// Round 1
// baseline (210.258 us; speedup 1.0000x reference)
//
#include <hip/hip_runtime.h>
#include <math.h>

// Problem constants
constexpr int B_  = 4;
constexpr int C_  = 256;
constexpr int HW_ = 4096;   // 64*64
constexpr int CR_ = 16;     // c / RED
constexpr int CQ_ = 32;     // c / 8
constexpr int NDB = 512;    // grid: 4b x 8cp x 16pt; 2 blocks/CU co-resident

__device__ unsigned g_cnt[8];   // zero-init at module load; monotonic barrier counters

__device__ __forceinline__ float sigmoidf_(float x){ return 1.f/(1.f+expf(-x)); }

// Monotonic device barrier: each dispatch adds exactly NDB to g_cnt[idx], so the
// counter is always a multiple of NDB at dispatch start (no init kernel needed;
// robust to ws poisoning and rocprof dispatch replay). NDB must be a power of 2.
__device__ __forceinline__ void dbar(int idx){
  __syncthreads();
  if (threadIdx.x == 0){
    __threadfence();
    unsigned old = __hip_atomic_fetch_add(&g_cnt[idx], 1u, __ATOMIC_RELEASE, __HIP_MEMORY_SCOPE_AGENT);
    unsigned tgt = (old & ~(unsigned)(NDB-1)) + (unsigned)NDB;
    while ((int)(__hip_atomic_load(&g_cnt[idx], __ATOMIC_ACQUIRE, __HIP_MEMORY_SCOPE_AGENT) - tgt) < 0)
      __builtin_amdgcn_s_sleep(1);
    __threadfence();
  }
  __syncthreads();
}

// One persistent kernel. Block (b, cp, pt) owns channels [cp*32, cp*32+32) and
// pixels [pt*256, pt*256+256) (4 image rows). x chunk cached in LDS: HBM reads
// x exactly once, writes out exactly once.
//   Phase 1: load x chunk -> LDS; per-channel partial sum/max over 256 px -> ws
//   dbar(0)
//   Phase 2: reduce 16 partials -> per-(b,c) avg/max; channel MLP -> att (own 32);
//            per-pixel partial sum/max of x*att over own 32 channels -> ws
//   dbar(1)
//   Phase 3: reduce 8 channel-group partials for 10 halo rows; 7x7 conv -> sig
//   Phase 4: out = x(LDS) * att * sig
//   gamma!=0 only: dbar(2); qkv; dbar(3); softmax+PV (unchanged from prior version)
__global__ void __launch_bounds__(256, 2) kFused(
    const float* __restrict__ x,
    const float* __restrict__ w1,  const float* __restrict__ w2,
    const float* __restrict__ wsp, const float* __restrict__ gm,
    const float* __restrict__ wq, const float* __restrict__ bq,
    const float* __restrict__ wk, const float* __restrict__ bk,
    const float* __restrict__ wv, const float* __restrict__ bv,
    float* __restrict__ cps, float* __restrict__ cpm,
    float* __restrict__ sps, float* __restrict__ spm,
    float* __restrict__ qb, float* __restrict__ kb, float* __restrict__ vb,
    float* __restrict__ out){
  int bx = blockIdx.x;
  int b = bx >> 7, rem = bx & 127, pt = rem >> 3, cp = rem & 7;
  int t = threadIdx.x;
  int w = t >> 6, f4 = t & 63;          // wave id, lane-as-float4-index
  int c0 = cp*32;

  __shared__ union {
    struct {
      float4 sx4[32][64];               // 32 KB: x chunk [local ch][float4-of-4px]
      float sa[C_], sm[C_];             // per-(b,c) avg / max
      float pa[C_], pm[C_];             // MLP partials
      float hs[CR_];
      float satt[32];                   // channel att for own 32 channels
      float savg[10][64], smax[10][64]; // spatial stats incl. +-3 row halo
      float ssig[256];                  // conv sigmoid for own 256 px
      float swsp[98];
    } p;                                              // ~42.6 KB
    float sxq[C_*32];                                 // qkv phase (32 KB)
    struct { float sq[CQ_], red[8], sl[HW_]; } f;     // softmax phase (~16.5 KB)
  } S;

  if (t < 98) S.p.swsp[t] = wsp[t];

  // ---- Phase 1: x chunk -> LDS + per-channel partial sum/max ----
  const float4* x4 = (const float4*)x;
  size_t gbase = (size_t)(b*C_ + c0)*(HW_/4) + pt*64 + f4;
  float4 xv[8];
  #pragma unroll
  for (int ph = 0; ph < 8; ph++)
    xv[ph] = x4[gbase + (size_t)(ph*4 + w)*(HW_/4)];
  #pragma unroll
  for (int ph = 0; ph < 8; ph++){
    int cl = ph*4 + w;                  // wave-uniform local channel
    float4 v = xv[ph];
    S.p.sx4[cl][f4] = v;
    float s = v.x+v.y+v.z+v.w;
    float m = fmaxf(fmaxf(v.x,v.y), fmaxf(v.z,v.w));
    #pragma unroll
    for (int off = 32; off; off >>= 1){
      s += __shfl_down(s, off);
      m = fmaxf(m, __shfl_down(m, off));
    }
    if (f4 == 0){
      cps[(b*C_ + c0 + cl)*16 + pt] = s;
      cpm[(b*C_ + c0 + cl)*16 + pt] = m;
    }
  }
  dbar(0);

  // ---- Phase 2a: full per-(b,c) avg/max (all 256 channels of own b) ----
  {
    const float4* ps4 = (const float4*)(cps + (b*C_ + t)*16);
    const float4* pm4 = (const float4*)(cpm + (b*C_ + t)*16);
    float s = 0.f, m = -INFINITY;
    #pragma unroll
    for (int k2 = 0; k2 < 4; k2++){
      float4 a = ps4[k2], c = pm4[k2];
      s += a.x+a.y+a.z+a.w;
      m = fmaxf(m, fmaxf(fmaxf(c.x,c.y), fmaxf(c.z,c.w)));
    }
    S.p.sa[t] = s * (1.f/HW_);
    S.p.sm[t] = m;
  }
  __syncthreads();
  // ---- Phase 2b: channel MLP (relu(h_avg)+relu(h_max) through shared w2) ----
  {
    int h = t >> 4, seg = t & 15;       // 16 hidden x 16 channel-segments
    float qa = 0.f, qm = 0.f;
    #pragma unroll
    for (int c2 = 0; c2 < 16; c2++){
      int c = seg*16 + c2;
      float ww = w1[h*C_ + c];
      qa += ww*S.p.sa[c]; qm += ww*S.p.sm[c];
    }
    S.p.pa[t] = qa; S.p.pm[t] = qm;
  }
  __syncthreads();
  if (t < CR_){
    float ha = 0.f, hm = 0.f;
    #pragma unroll
    for (int s2 = 0; s2 < 16; s2++){ ha += S.p.pa[t*16+s2]; hm += S.p.pm[t*16+s2]; }
    S.p.hs[t] = fmaxf(ha, 0.f) + fmaxf(hm, 0.f);
  }
  __syncthreads();
  if (t < 32){
    float o = 0.f;
    #pragma unroll
    for (int h2 = 0; h2 < CR_; h2++) o += S.p.hs[h2]*w2[(c0+t)*CR_+h2];
    S.p.satt[t] = sigmoidf_(o);
  }
  __syncthreads();
  // ---- Phase 2c: per-pixel partials of x*att over own 32 channels ----
  {
    const float* sxF = (const float*)S.p.sx4;   // [32][256] floats
    float s = 0.f, m = -INFINITY;
    #pragma unroll
    for (int j = 0; j < 32; j++){
      float v = sxF[j*256 + t] * S.p.satt[j];
      s += v; m = fmaxf(m, v);
    }
    sps[(size_t)(b*8 + cp)*HW_ + pt*256 + t] = s;
    spm[(size_t)(b*8 + cp)*HW_ + pt*256 + t] = m;
  }
  dbar(1);

  // ---- Phase 3: reduce 8 group-partials for 10 halo rows, 7x7 conv ----
  for (int idx = t; idx < 640; idx += 256){
    int row = idx >> 6, col = idx & 63;
    int gr = pt*4 - 3 + row;            // global image row (zero-padded)
    float s = 0.f, m = 0.f;
    if ((unsigned)gr < 64u){
      float ss = 0.f, mm = -INFINITY;
      #pragma unroll
      for (int g2 = 0; g2 < 8; g2++){
        ss += sps[(size_t)(b*8+g2)*HW_ + gr*64 + col];
        mm = fmaxf(mm, spm[(size_t)(b*8+g2)*HW_ + gr*64 + col]);
      }
      s = ss * (1.f/C_); m = mm;
    }
    S.p.savg[row][col] = s; S.p.smax[row][col] = m;
  }
  __syncthreads();
  {
    int trow = t >> 6, col = t & 63;
    float acc = 0.f;
    #pragma unroll
    for (int ky = 0; ky < 7; ky++){
      #pragma unroll
      for (int kx = 0; kx < 7; kx++){
        int gx = col - 3 + kx;
        if ((unsigned)gx < 64u)
          acc += S.p.savg[trow+ky][gx]*S.p.swsp[ky*7+kx]
               + S.p.smax[trow+ky][gx]*S.p.swsp[49+ky*7+kx];
      }
    }
    S.p.ssig[t] = sigmoidf_(acc);       // px = trow*64+col = t
  }
  __syncthreads();

  // ---- Phase 4: out = x * att * sig (all from LDS) ----
  float g = gm[0];
  {
    float4 sg = ((const float4*)S.p.ssig)[f4];
    float4* o4 = (float4*)out;
    #pragma unroll
    for (int ph = 0; ph < 8; ph++){
      int cl = ph*4 + w;
      float a = S.p.satt[cl];
      float4 v = S.p.sx4[cl][f4];
      float4 rr;
      rr.x = v.x*a*sg.x; rr.y = v.y*a*sg.y; rr.z = v.z*a*sg.z; rr.w = v.w*a*sg.w;
      o4[gbase + (size_t)cl*(HW_/4)] = rr;
    }
  }

  // ---- Gated non-local attention (uniform branch; gamma==0 -> done) ----
  if (g == 0.f) return;
  dbar(2);                              // out fully visible device-wide

  // qkv: one 32-px tile per block (512 tiles total)
  {
    int tile = bx & 127, p0 = tile*32;
    for (int idx = t; idx < C_*32; idx += 256){
      int c = idx >> 5, px = idx & 31;
      S.sxq[idx] = out[(size_t)(b*C_+c)*HW_ + p0 + px];
    }
    __syncthreads();
    for (int oi = t; oi < CQ_*32; oi += 256){
      int o = oi >> 5, px = oi & 31;
      float aq = bq[o], ak = bk[o];
      for (int c = 0; c < C_; c++){ float xvv = S.sxq[c*32+px]; aq += xvv*wq[o*C_+c]; ak += xvv*wk[o*C_+c]; }
      qb[(size_t)(b*CQ_+o)*HW_ + p0 + px] = aq;
      kb[(size_t)(b*CQ_+o)*HW_ + p0 + px] = ak;
    }
    for (int oi = t; oi < C_*32; oi += 256){
      int o = oi >> 5, px = oi & 31;
      float av = bv[o];
      for (int c = 0; c < C_; c++) av += S.sxq[c*32+px]*wv[o*C_+c];
      vb[(size_t)(b*C_+o)*HW_ + p0 + px] = av;
    }
    __syncthreads();
  }
  dbar(3);                              // qkv complete

  for (int gi = bx; gi < B_*HW_; gi += NDB){
    int b2 = gi >> 12, i = gi & (HW_-1);
    if (t < CQ_) S.f.sq[t] = qb[(size_t)(b2*CQ_+t)*HW_ + i];
    __syncthreads();
    float lmax = -INFINITY;
    for (int j = t; j < HW_; j += 256){
      float l = 0.f;
      for (int d = 0; d < CQ_; d++) l += S.f.sq[d]*kb[(size_t)(b2*CQ_+d)*HW_ + j];
      S.f.sl[j] = l; lmax = fmaxf(lmax, l);
    }
    for (int off = 32; off; off >>= 1) lmax = fmaxf(lmax, __shfl_down(lmax, off));
    if (!(t & 63)) S.f.red[t>>6] = lmax;
    __syncthreads();
    float M = fmaxf(fmaxf(S.f.red[0],S.f.red[1]), fmaxf(S.f.red[2],S.f.red[3]));
    float lsum = 0.f;
    for (int j = t; j < HW_; j += 256){ float pv = expf(S.f.sl[j]-M); S.f.sl[j] = pv; lsum += pv; }
    for (int off = 32; off; off >>= 1) lsum += __shfl_down(lsum, off);
    if (!(t & 63)) S.f.red[4+(t>>6)] = lsum;
    __syncthreads();
    float inv = g/(S.f.red[4]+S.f.red[5]+S.f.red[6]+S.f.red[7]);
    float acc2 = 0.f;
    const float* vrow = vb + (size_t)(b2*C_+t)*HW_;
    for (int j = 0; j < HW_; j++) acc2 += S.f.sl[j]*vrow[j];
    out[(size_t)(b2*C_+t)*HW_ + i] += acc2*inv;
    __syncthreads();
  }
}

extern "C" void kernel_launch(void* const* d_in, const int* in_sizes, int n_in,
                              void* d_out, int out_size, void* d_ws, size_t ws_size,
                              hipStream_t stream){
  const float* x   = (const float*)d_in[0];
  const float* w1  = (const float*)d_in[1];
  const float* w2  = (const float*)d_in[2];
  const float* wsp = (const float*)d_in[3];
  const float* wq  = (const float*)d_in[4];
  const float* bq  = (const float*)d_in[5];
  const float* wk  = (const float*)d_in[6];
  const float* bk  = (const float*)d_in[7];
  const float* wv  = (const float*)d_in[8];
  const float* bv  = (const float*)d_in[9];
  const float* gm  = (const float*)d_in[10];
  float* out = (float*)d_out;
  float* ws  = (float*)d_ws;

  float* cps = ws;                         // B*C*16 = 16384
  float* cpm = cps + B_*C_*16;             // 16384
  float* sps = cpm + B_*C_*16;             // B*8*HW = 131072
  float* spm = sps + (size_t)B_*8*HW_;     // 131072
  float* qb  = spm + (size_t)B_*8*HW_;     // B*CQ*HW = 524288 (gated)
  float* kb  = qb  + (size_t)B_*CQ_*HW_;   // 524288 (gated)
  float* vb  = kb  + (size_t)B_*CQ_*HW_;   // B*C*HW = 4194304 (gated)
  (void)in_sizes; (void)n_in; (void)out_size; (void)ws_size;

  kFused<<<NDB, 256, 0, stream>>>(x, w1, w2, wsp, gm,
                                  wq, bq, wk, bk, wv, bv,
                                  cps, cpm, sps, spm, qb, kb, vb, out);
}

// Round 2
// 104.466 us; speedup vs baseline: 2.0127x; 2.0127x over previous
//
#include <hip/hip_runtime.h>
#include <math.h>

// Problem constants
constexpr int B_  = 4;
constexpr int C_  = 256;
constexpr int HW_ = 4096;   // 64*64
constexpr int CR_ = 16;     // c / RED
constexpr int CQ_ = 32;     // c / 8
constexpr int NDB = 512;    // kD3 grid (2 blocks/CU, co-resident via launch_bounds)

__device__ __forceinline__ float sigmoidf_(float x){ return 1.f/(1.f+expf(-x)); }

// NOTE (round 1 lesson): a 512-block agent-scope spin barrier costs ~60 us on
// MI355X (measured: fused kernel 138 us with VALUBusy 2.3%, all waiting).
// Kernel-launch boundaries provide the same cross-block ordering for ~1 us.
// So the pipeline stays as 3 stream-ordered kernels; the device barrier is
// used ONLY on the gamma!=0 path (never taken here), matching the reference.

// ---- A: per (b,c) mean & max over hw. grid = B*C = 1024 blocks, 256 thr ----
__global__ void kA(const float* __restrict__ x, float* __restrict__ avg, float* __restrict__ mxv){
  int bc = blockIdx.x;
  const float4* r4 = (const float4*)(x + (size_t)bc*HW_);
  // Issue all 4 cold HBM loads first, then reduce (max outstanding loads).
  float4 v0 = r4[threadIdx.x];
  float4 v1 = r4[threadIdx.x + 256];
  float4 v2 = r4[threadIdx.x + 512];
  float4 v3 = r4[threadIdx.x + 768];
  float s = (v0.x+v0.y+v0.z+v0.w) + (v1.x+v1.y+v1.z+v1.w)
          + (v2.x+v2.y+v2.z+v2.w) + (v3.x+v3.y+v3.z+v3.w);
  float m = fmaxf(fmaxf(fmaxf(v0.x,v0.y), fmaxf(v0.z,v0.w)),
                  fmaxf(fmaxf(v1.x,v1.y), fmaxf(v1.z,v1.w)));
  m = fmaxf(m, fmaxf(fmaxf(fmaxf(v2.x,v2.y), fmaxf(v2.z,v2.w)),
                     fmaxf(fmaxf(v3.x,v3.y), fmaxf(v3.z,v3.w))));
  for (int off = 32; off; off >>= 1){
    s += __shfl_down(s, off);
    m = fmaxf(m, __shfl_down(m, off));
  }
  __shared__ float ss[4], sm[4];
  int w = threadIdx.x >> 6, lane = threadIdx.x & 63;
  if (!lane){ ss[w] = s; sm[w] = m; }
  __syncthreads();
  if (!threadIdx.x){
    avg[bc] = (ss[0]+ss[1]+ss[2]+ss[3]) * (1.f/HW_);
    mxv[bc] = fmaxf(fmaxf(sm[0],sm[1]), fmaxf(sm[2],sm[3]));
  }
}

// ---- BC: channel-MLP -> satt (stored to attg), then per-row spatial stats.
//      grid = B*64 rows = 256 blocks. x loads issued EARLY (overlap w/ MLP). ----
__global__ void kBC(const float* __restrict__ x,
                    const float* __restrict__ avg, const float* __restrict__ mxv,
                    const float* __restrict__ w1,  const float* __restrict__ w2,
                    float* __restrict__ attg,
                    float* __restrict__ avgs, float* __restrict__ maxs,
                    int* __restrict__ cnt){
  int b = blockIdx.x >> 6, r = blockIdx.x & 63, t = threadIdx.x;
  if (blockIdx.x == 0 && t == 0) cnt[0] = 0;    // reset kD3 barrier (stream order)
  __shared__ float sa[C_], sm[C_], pa[C_], pm[C_], hs[CR_], satt[C_];
  __shared__ float4 rs[16][16], rm[16][16];

  // EARLY: issue the 16 x-tile loads; latency hides behind the MLP below.
  int cg = t >> 4, q = t & 15;
  const float4* xb = (const float4*)x + (size_t)(b*C_ + cg*16)*(HW_/4) + (r<<4) + q;
  float4 xv[16];
  #pragma unroll
  for (int j = 0; j < 16; j++) xv[j] = xb[(size_t)j*(HW_/4)];

  sa[t] = avg[b*C_+t]; sm[t] = mxv[b*C_+t];
  __syncthreads();
  int h = t >> 4, seg = t & 15;                 // 16 hidden x 16 channel-segments
  float qa = 0.f, qm = 0.f;
  #pragma unroll
  for (int c2 = 0; c2 < 16; c2++){
    int c = seg*16 + c2;
    float ww = w1[h*C_ + c];
    qa += ww*sa[c]; qm += ww*sm[c];
  }
  pa[t] = qa; pm[t] = qm;
  __syncthreads();
  if (t < CR_){
    float ha = 0.f, hm = 0.f;
    #pragma unroll
    for (int s2 = 0; s2 < 16; s2++){ ha += pa[t*16+s2]; hm += pm[t*16+s2]; }
    hs[t] = fmaxf(ha, 0.f) + fmaxf(hm, 0.f);    // relu(h_avg)+relu(h_max), shared w2
  }
  __syncthreads();
  float o = 0.f;
  #pragma unroll
  for (int h2 = 0; h2 < CR_; h2++) o += hs[h2]*w2[t*CR_+h2];   // w2 is [C, CR]
  float attv = sigmoidf_(o);
  satt[t] = attv;
  if (r == 0) attg[b*C_+t] = attv;              // one writer per (b,c)
  __syncthreads();

  // per-row channel mean/max of x*att (x already in registers)
  float4 s = {0.f,0.f,0.f,0.f};
  float4 m = {-INFINITY,-INFINITY,-INFINITY,-INFINITY};
  #pragma unroll
  for (int j = 0; j < 16; j++){
    float a = satt[cg*16 + j];
    float vx=xv[j].x*a, vy=xv[j].y*a, vz=xv[j].z*a, vw=xv[j].w*a;
    s.x+=vx; s.y+=vy; s.z+=vz; s.w+=vw;
    m.x=fmaxf(m.x,vx); m.y=fmaxf(m.y,vy); m.z=fmaxf(m.z,vz); m.w=fmaxf(m.w,vw);
  }
  rs[cg][q] = s; rm[cg][q] = m;
  __syncthreads();
  if (t < 16){
    float4 Sv = {0.f,0.f,0.f,0.f};
    float4 Mv = {-INFINITY,-INFINITY,-INFINITY,-INFINITY};
    #pragma unroll
    for (int g2 = 0; g2 < 16; g2++){
      float4 a = rs[g2][t], b2 = rm[g2][t];
      Sv.x+=a.x; Sv.y+=a.y; Sv.z+=a.z; Sv.w+=a.w;
      Mv.x=fmaxf(Mv.x,b2.x); Mv.y=fmaxf(Mv.y,b2.y); Mv.z=fmaxf(Mv.z,b2.z); Mv.w=fmaxf(Mv.w,b2.w);
    }
    Sv.x*=(1.f/C_); Sv.y*=(1.f/C_); Sv.z*=(1.f/C_); Sv.w*=(1.f/C_);
    ((float4*)(avgs + b*HW_ + r*64))[t] = Sv;
    ((float4*)(maxs + b*HW_ + r*64))[t] = Mv;
  }
}

// ---- D3: halo stage + 7x7 conv + sigmoid + out = x*att*sig, THEN (gated)
//      non-local attention with in-kernel device barrier. grid = 512 blocks
//      (2/CU co-resident), 32 channels/block. ----
__global__ void __launch_bounds__(256, 2) kD3(
    const float* __restrict__ x, const float* __restrict__ attg,
    const float* __restrict__ avgs, const float* __restrict__ maxs,
    const float* __restrict__ wsp, const float* __restrict__ gm,
    const float* __restrict__ wq, const float* __restrict__ bq,
    const float* __restrict__ wk, const float* __restrict__ bk,
    const float* __restrict__ wv, const float* __restrict__ bv,
    float* __restrict__ qb, float* __restrict__ kb, float* __restrict__ vb,
    float* __restrict__ out, int* __restrict__ cnt){
  int bx = blockIdx.x;
  int b = bx >> 7, rem = bx & 127, rt = rem >> 3, cp = rem & 7;
  int t = threadIdx.x;
  __shared__ union {
    struct {
      float savg[10][64], smax[10][64], ssig[4][64], satt[32], swsp[98];
    } p;                                              // conv phase (~6.8 KB)
    float sx[C_*32];                                  // qkv phase (32 KB)
    struct { float sq[CQ_], red[8], sl[HW_]; } f;     // softmax phase (~16.5 KB)
  } S;

  // EARLY: issue the 8 x-tile loads; latency hides behind staging + conv.
  int f4id = t & 63;
  int imgo = rt*64 + f4id;                      // float4 index within image
  const float4* x4 = (const float4*)x;
  float4 xv[8];
  {
    size_t g0 = (size_t)(b*C_ + cp*32 + (t>>6))*(HW_/4) + imgo;
    #pragma unroll
    for (int jj = 0; jj < 8; jj++) xv[jj] = x4[g0 + (size_t)jj*4*(HW_/4)];
  }

  if (t < 98) S.p.swsp[t] = wsp[t];
  if (t < 32) S.p.satt[t] = attg[b*C_ + cp*32 + t];
  for (int idx = t; idx < 640; idx += 256){
    int row = idx >> 6, col = idx & 63;
    int gr = rt*4 - 3 + row;                    // global image row (zero-padded)
    float s = 0.f, m = 0.f;
    if ((unsigned)gr < 64u){
      s = avgs[b*HW_ + gr*64 + col];
      m = maxs[b*HW_ + gr*64 + col];
    }
    S.p.savg[row][col] = s; S.p.smax[row][col] = m;
  }
  __syncthreads();
  int trow = t >> 6, col = t & 63;
  float acc = 0.f;
  #pragma unroll
  for (int ky = 0; ky < 7; ky++){
    #pragma unroll
    for (int kx = 0; kx < 7; kx++){
      int gx = col - 3 + kx;
      if ((unsigned)gx < 64u)
        acc += S.p.savg[trow+ky][gx]*S.p.swsp[ky*7+kx]
             + S.p.smax[trow+ky][gx]*S.p.swsp[49+ky*7+kx];
    }
  }
  S.p.ssig[trow][col] = sigmoidf_(acc);
  __syncthreads();
  float4 sg4 = ((const float4*)S.p.ssig)[f4id];
  float4* o4 = (float4*)out;
  #pragma unroll
  for (int jj = 0; jj < 8; jj++){
    int lc = (t>>6) + jj*4;                     // local channel (wave-uniform)
    float a = S.p.satt[lc];
    size_t g = (size_t)(b*C_ + cp*32 + lc)*(HW_/4) + imgo;
    float4 rr;
    rr.x = xv[jj].x*a*sg4.x; rr.y = xv[jj].y*a*sg4.y;
    rr.z = xv[jj].z*a*sg4.z; rr.w = xv[jj].w*a*sg4.w;
    o4[g] = rr;
  }

  // ---- Gated non-local attention (uniform branch; gamma==0 -> done) ----
  float g = gm[0];
  if (g == 0.f) return;

  // device barrier: out fully written before qkv reads (gamma!=0 path only)
  __syncthreads();
  if (t == 0){
    __threadfence();
    __hip_atomic_fetch_add(cnt, 1, __ATOMIC_RELEASE, __HIP_MEMORY_SCOPE_AGENT);
    while (__hip_atomic_load(cnt, __ATOMIC_ACQUIRE, __HIP_MEMORY_SCOPE_AGENT) < NDB)
      __builtin_amdgcn_s_sleep(1);
    __threadfence();
  }
  __syncthreads();

  // qkv: one 32-px tile per block (512 tiles total)
  {
    int b2 = bx >> 7, tile = bx & 127, p0 = tile*32;
    for (int idx = t; idx < C_*32; idx += 256){
      int c = idx >> 5, px = idx & 31;
      S.sx[idx] = out[(size_t)(b2*C_+c)*HW_ + p0 + px];
    }
    __syncthreads();
    for (int oi = t; oi < CQ_*32; oi += 256){
      int o = oi >> 5, px = oi & 31;
      float aq = bq[o], ak = bk[o];
      for (int c = 0; c < C_; c++){ float xvv = S.sx[c*32+px]; aq += xvv*wq[o*C_+c]; ak += xvv*wk[o*C_+c]; }
      qb[(size_t)(b2*CQ_+o)*HW_ + p0 + px] = aq;
      kb[(size_t)(b2*CQ_+o)*HW_ + p0 + px] = ak;
    }
    for (int oi = t; oi < C_*32; oi += 256){
      int o = oi >> 5, px = oi & 31;
      float av = bv[o];
      for (int c = 0; c < C_; c++) av += S.sx[c*32+px]*wv[o*C_+c];
      vb[(size_t)(b2*C_+o)*HW_ + p0 + px] = av;
    }
    __syncthreads();
  }

  // second barrier: qkv complete before softmax consumes k/v of other tiles
  if (t == 0){
    __threadfence();
    __hip_atomic_fetch_add(cnt, 1, __ATOMIC_RELEASE, __HIP_MEMORY_SCOPE_AGENT);
    while (__hip_atomic_load(cnt, __ATOMIC_ACQUIRE, __HIP_MEMORY_SCOPE_AGENT) < 2*NDB)
      __builtin_amdgcn_s_sleep(1);
    __threadfence();
  }
  __syncthreads();

  for (int gi = bx; gi < B_*HW_; gi += NDB){
    int b2 = gi >> 12, i = gi & (HW_-1);
    if (t < CQ_) S.f.sq[t] = qb[(size_t)(b2*CQ_+t)*HW_ + i];
    __syncthreads();
    float lmax = -INFINITY;
    for (int j = t; j < HW_; j += 256){
      float l = 0.f;
      for (int d = 0; d < CQ_; d++) l += S.f.sq[d]*kb[(size_t)(b2*CQ_+d)*HW_ + j];
      S.f.sl[j] = l; lmax = fmaxf(lmax, l);
    }
    for (int off = 32; off; off >>= 1) lmax = fmaxf(lmax, __shfl_down(lmax, off));
    if (!(t & 63)) S.f.red[t>>6] = lmax;
    __syncthreads();
    float M = fmaxf(fmaxf(S.f.red[0],S.f.red[1]), fmaxf(S.f.red[2],S.f.red[3]));
    float lsum = 0.f;
    for (int j = t; j < HW_; j += 256){ float p = expf(S.f.sl[j]-M); S.f.sl[j] = p; lsum += p; }
    for (int off = 32; off; off >>= 1) lsum += __shfl_down(lsum, off);
    if (!(t & 63)) S.f.red[4+(t>>6)] = lsum;
    __syncthreads();
    float inv = g/(S.f.red[4]+S.f.red[5]+S.f.red[6]+S.f.red[7]);
    float acc2 = 0.f;
    const float* vrow = vb + (size_t)(b2*C_+t)*HW_;
    for (int j = 0; j < HW_; j++) acc2 += S.f.sl[j]*vrow[j];
    out[(size_t)(b2*C_+t)*HW_ + i] += acc2*inv;
    __syncthreads();
  }
}

extern "C" void kernel_launch(void* const* d_in, const int* in_sizes, int n_in,
                              void* d_out, int out_size, void* d_ws, size_t ws_size,
                              hipStream_t stream){
  const float* x   = (const float*)d_in[0];
  const float* w1  = (const float*)d_in[1];
  const float* w2  = (const float*)d_in[2];
  const float* wsp = (const float*)d_in[3];
  const float* wq  = (const float*)d_in[4];
  const float* bq  = (const float*)d_in[5];
  const float* wk  = (const float*)d_in[6];
  const float* bk  = (const float*)d_in[7];
  const float* wv  = (const float*)d_in[8];
  const float* bv  = (const float*)d_in[9];
  const float* gm  = (const float*)d_in[10];
  float* out = (float*)d_out;
  float* ws  = (float*)d_ws;

  int*   cnt  = (int*)ws;                 // 64 B barrier region
  float* avg  = ws + 16;                  // 1024
  float* mxv  = avg  + B_*C_;             // 1024
  float* attg = mxv  + B_*C_;             // 1024
  float* avgs = attg + B_*C_;             // B*HW = 16384
  float* maxs = avgs + B_*HW_;            // 16384
  float* qb   = maxs + B_*HW_;            // B*CQ*HW = 524288 (gated)
  float* kb   = qb   + B_*CQ_*HW_;        // 524288 (gated)
  float* vb   = kb   + B_*CQ_*HW_;        // B*C*HW = 4194304 (gated)
  (void)in_sizes; (void)n_in; (void)out_size; (void)ws_size;

  kA <<<B_*C_, 256, 0, stream>>>(x, avg, mxv);
  kBC<<<256,   256, 0, stream>>>(x, avg, mxv, w1, w2, attg, avgs, maxs, cnt);
  kD3<<<NDB,   256, 0, stream>>>(x, attg, avgs, maxs, wsp, gm,
                                 wq, bq, wk, bk, wv, bv, qb, kb, vb, out, cnt);
}